// Round 10
// baseline (357.608 us; speedup 1.0000x reference)
//
#include <hip/hip_runtime.h>
#include <hip/hip_bf16.h>
#include <stdint.h>
#include <stddef.h>

// Problem constants (fixed by the reference)
#define B_DIM 4
#define NH    16
#define LSEQ  2048
#define HD    64
#define DM    1024
#define TOKENS (B_DIM * LSEQ)   // 8192

typedef __bf16 bf16_t;
typedef __attribute__((ext_vector_type(8))) __bf16 bf16x8;
typedef __attribute__((ext_vector_type(4))) __bf16 bf16x4;
typedef __attribute__((ext_vector_type(4))) float  f32x4;

// async global->LDS, 16B per lane, lane i lands at ldsbase + i*16
#define GLD16(gp, lp) \
  __builtin_amdgcn_global_load_lds((__attribute__((address_space(1))) void*)(gp), \
                                   (__attribute__((address_space(3))) void*)(lp), 16, 0, 0)

// raw sync primitives (T4: counted vmcnt, NEVER vmcnt(0) drain in main loop)
#define WAITV4 asm volatile("s_waitcnt vmcnt(4)" ::: "memory")
#define WAITV0 asm volatile("s_waitcnt vmcnt(0)" ::: "memory")
#define WAITL0 asm volatile("s_waitcnt lgkmcnt(0)" ::: "memory")
#define SBAR   __builtin_amdgcn_s_barrier()
#define SCHED0 __builtin_amdgcn_sched_barrier(0)

__device__ __forceinline__ f32x4 mfma_16x16x32(bf16x8 a, bf16x8 b, f32x4 c) {
  return __builtin_amdgcn_mfma_f32_16x16x32_bf16(a, b, c, 0, 0, 0);
}

// ---------------------------------------------------------------------------
// Fused prep kernel (ONE dispatch, r6-proven): 1D grid decode.
//  [0, 24576)       : 3 activation casts f32->bf16 (q,k,v -> xq,xk,xv)
//  [24576, 28672)   : 4 weight casts f32->bf16 (Wq,Wk,Wv,Wo)
//  [28672, 29696)   : 2 interleaved (cos,sin) float2 tables (q,k) in d_out
// ---------------------------------------------------------------------------
__global__ __launch_bounds__(256) void prep_kernel(const float* __restrict__ q,
                                                   const float* __restrict__ k,
                                                   const float* __restrict__ v,
                                                   const float* __restrict__ Wq,
                                                   const float* __restrict__ Wk,
                                                   const float* __restrict__ Wv,
                                                   const float* __restrict__ Wo,
                                                   const float* __restrict__ cos_q,
                                                   const float* __restrict__ sin_q,
                                                   const float* __restrict__ cos_k,
                                                   const float* __restrict__ sin_k,
                                                   bf16_t* __restrict__ xdst,
                                                   bf16_t* __restrict__ wdst,
                                                   float2* __restrict__ cs) {
  const int bid = blockIdx.x;
  const int tid = threadIdx.x;
  if (bid < 24576) {                      // activation casts, n = TOKENS*DM
    const int s = bid >> 13, off = bid & 8191;
    const float* src = (s == 0) ? q : (s == 1) ? k : v;
    const int i = (off * 256 + tid) * 4;
    const float4 val = *(const float4*)(src + i);
    bf16x4 o;
    o[0] = (bf16_t)val.x; o[1] = (bf16_t)val.y; o[2] = (bf16_t)val.z; o[3] = (bf16_t)val.w;
    *(bf16x4*)(xdst + (size_t)s * (TOKENS * (size_t)DM) + i) = o;
  } else if (bid < 28672) {               // weight casts, n = DM*DM
    const int s = (bid - 24576) >> 10, off = (bid - 24576) & 1023;
    const float* src = (s == 0) ? Wq : (s == 1) ? Wk : (s == 2) ? Wv : Wo;
    const int i = (off * 256 + tid) * 4;
    const float4 val = *(const float4*)(src + i);
    bf16x4 o;
    o[0] = (bf16_t)val.x; o[1] = (bf16_t)val.y; o[2] = (bf16_t)val.z; o[3] = (bf16_t)val.w;
    *(bf16x4*)(wdst + (size_t)s * (DM * (size_t)DM) + i) = o;
  } else {                                // cs tables, n = TOKENS*HD = 524288
    const int s = (bid - 28672) >> 9, off = (bid - 28672) & 511;
    const float* cp = (s == 0) ? cos_q : cos_k;
    const float* sp = (s == 0) ? sin_q : sin_k;
    const int i = (off * 256 + tid) * 4;
    const float4 c4 = *(const float4*)(cp + i);
    const float4 s4 = *(const float4*)(sp + i);
    float2* d = cs + (size_t)s * (TOKENS * (size_t)HD) + i;
    d[0] = make_float2(c4.x, s4.x);
    d[1] = make_float2(c4.y, s4.y);
    d[2] = make_float2(c4.z, s4.z);
    d[3] = make_float2(c4.w, s4.w);
  }
}

// GEMM tile body (r6-proven config, frozen): 128x128 tile, 2-deep
// counted-vmcnt pipeline. At the 2-phase structural ceiling (m233 ~607 TF);
// r5/r7/r8 structural escapes all measured worse.
#define GEMM_TILE(CUR, WAIT, PRE, KK2)                                        \
  {                                                                           \
    WAIT; SBAR; SCHED0;                                                       \
    const bf16_t* Ac = &As[CUR][0];                                           \
    const bf16_t* Bc = &Bs[CUR][0];                                           \
    bf16x8 af[4], bfr[4];                                                     \
    _Pragma("unroll") for (int i_ = 0; i_ < 4; ++i_)                          \
      af[i_] = *(const bf16x8*)(Ac + (wm + i_ * 16 + l16) * 32 + fcol);       \
    _Pragma("unroll") for (int j_ = 0; j_ < 4; ++j_)                          \
      bfr[j_] = *(const bf16x8*)(Bc + (wn + j_ * 16 + l16) * 32 + fcol);      \
    _Pragma("unroll") for (int i_ = 0; i_ < 4; ++i_)                          \
      _Pragma("unroll") for (int j_ = 0; j_ < 4; ++j_)                        \
        acc[i_][j_] = mfma_16x16x32(af[i_], bfr[j_], acc[i_][j_]);            \
    WAITL0; SBAR; SCHED0;                                                     \
    if (PRE) {                                                                \
      const int kk2_ = (KK2);                                                 \
      GLD16(Ag0 + kk2_, &As[CUR][0] + ld0);                                   \
      GLD16(Ag1 + kk2_, &As[CUR][0] + ld1);                                   \
      GLD16(Bg0 + kk2_, &Bs[CUR][0] + ld0);                                   \
      GLD16(Bg1 + kk2_, &Bs[CUR][0] + ld1);                                   \
    }                                                                         \
  }

#define GEMM_LOOP                                                             \
  GLD16(Ag0, &As[0][0] + ld0); GLD16(Ag1, &As[0][0] + ld1);                   \
  GLD16(Bg0, &Bs[0][0] + ld0); GLD16(Bg1, &Bs[0][0] + ld1);                   \
  GLD16(Ag0 + 32, &As[1][0] + ld0); GLD16(Ag1 + 32, &As[1][0] + ld1);         \
  GLD16(Bg0 + 32, &Bs[1][0] + ld0); GLD16(Bg1 + 32, &Bs[1][0] + ld1);         \
  for (int ii = 0; ii < 15; ++ii) {                                           \
    const int kk2a = ii * 64 + 64;                                            \
    GEMM_TILE(0, WAITV4, true, kk2a);                                         \
    GEMM_TILE(1, WAITV4, true, kk2a + 32);                                    \
  }                                                                           \
  GEMM_TILE(0, WAITV4, false, 0);                                             \
  GEMM_TILE(1, WAITV0, false, 0);

// ---------------------------------------------------------------------------
// Fused QKV projection (r6-proven, frozen): ONE dispatch, blockIdx.z=q,k,v.
// ---------------------------------------------------------------------------
__global__ __launch_bounds__(256) void qkv_proj_kernel(const bf16_t* __restrict__ X,
                                                       const bf16_t* __restrict__ Wb,
                                                       const float* __restrict__ bq,
                                                       const float* __restrict__ bk,
                                                       const float* __restrict__ bv,
                                                       const float2* __restrict__ csq,
                                                       const float2* __restrict__ csk,
                                                       bf16_t* __restrict__ qtb,
                                                       bf16_t* __restrict__ ktb,
                                                       bf16_t* __restrict__ vtb) {
  __shared__ bf16_t As[2][128 * 32];
  __shared__ bf16_t Bs[2][128 * 32];
  const int z = blockIdx.z;
  const bf16_t* A  = X  + (size_t)z * TOKENS * DM;
  const bf16_t* Bw = Wb + (size_t)z * DM * DM;
  const float* bias = (z == 0) ? bq : (z == 1) ? bk : bv;

  const int tid  = threadIdx.x;
  const int wave = tid >> 6, lane = tid & 63;
  const int quad = lane >> 4, l16 = lane & 15;
  const int m0 = blockIdx.x * 128, n0 = blockIdx.y * 128;
  const int wm = (wave >> 1) * 64, wn = (wave & 1) * 64;

  f32x4 acc[4][4];
#pragma unroll
  for (int i = 0; i < 4; ++i)
#pragma unroll
    for (int j = 0; j < 4; ++j) acc[i][j] = (f32x4){0.f, 0.f, 0.f, 0.f};

  const int srow = lane >> 2;
  const int scol = ((lane & 3) ^ ((lane >> 3) & 3)) * 8;
  const int c0 = wave * 2, c1 = c0 + 1;
  const int r0 = c0 * 16 + srow, r1 = c1 * 16 + srow;
  const bf16_t* Ag0 = A  + (size_t)(m0 + r0) * DM + scol;
  const bf16_t* Ag1 = A  + (size_t)(m0 + r1) * DM + scol;
  const bf16_t* Bg0 = Bw + (size_t)(n0 + r0) * DM + scol;
  const bf16_t* Bg1 = Bw + (size_t)(n0 + r1) * DM + scol;
  const int ld0 = c0 * 512, ld1 = c1 * 512;

  const int fcol = ((quad ^ ((l16 >> 1) & 3)) << 3);

  GEMM_LOOP

  // epilogue: C row = quad*4+reg, col = l16 (m89-verified C/D layout)
  if (z < 2) {
    const float2* cst = (z == 0) ? csq : csk;
    bf16_t* out = (z == 0) ? qtb : ktb;
    const int h = (n0 + wn) >> 6;
#pragma unroll
    for (int i = 0; i < 4; ++i) {
#pragma unroll
      for (int j = 0; j < 2; ++j) {
        const int hd1 = j * 16 + l16;
        const int hd2 = hd1 + 32;
        const float bn1 = bias[n0 + wn + hd1];
        const float bn2 = bias[n0 + wn + hd2];
#pragma unroll
        for (int r = 0; r < 4; ++r) {
          const int m = m0 + wm + i * 16 + quad * 4 + r;
          const int b = m >> 11, l = m & (LSEQ - 1);
          const size_t cb = ((size_t)b * LSEQ + l) * HD;
          // explicit bf16 round BEFORE rope (verified numerics)
          const float x1 = (float)(bf16_t)(acc[i][j][r] + bn1);
          const float x2 = (float)(bf16_t)(acc[i][j + 2][r] + bn2);
          const float2 cs1 = cst[cb + hd1];
          const float2 cs2 = cst[cb + hd2];
          bf16_t* dst = out + (((size_t)(b * NH + h)) * LSEQ + l) * HD;
          dst[hd1] = (bf16_t)(x1 * cs1.x - x2 * cs1.y);
          dst[hd2] = (bf16_t)(x2 * cs2.x + x1 * cs2.y);
        }
      }
    }
  } else {
#pragma unroll
    for (int i = 0; i < 4; ++i) {
      const int mb = m0 + wm + i * 16 + quad * 4;
      const int b = mb >> 11, l = mb & (LSEQ - 1);
#pragma unroll
      for (int j = 0; j < 4; ++j) {
        const int n = n0 + wn + j * 16 + l16;
        const int h = n >> 6, hd = n & (HD - 1);
        const float bn = bias[n];
        bf16x4 pk;
#pragma unroll
        for (int r = 0; r < 4; ++r) pk[r] = (bf16_t)(acc[i][j][r] + bn);
        *(bf16x4*)(vtb + (((size_t)(b * NH + h)) * HD + hd) * LSEQ + l) = pk;
      }
    }
  }
}

// ---------------------------------------------------------------------------
// Out projection: C = A * Wo^T + bo, f32 store (r6-proven, frozen)
// ---------------------------------------------------------------------------
__global__ __launch_bounds__(256) void out_gemm_kernel(const bf16_t* __restrict__ A,
                                                       const bf16_t* __restrict__ Bw,
                                                       const float* __restrict__ bias,
                                                       float* __restrict__ out) {
  __shared__ bf16_t As[2][128 * 32];
  __shared__ bf16_t Bs[2][128 * 32];
  const int tid  = threadIdx.x;
  const int wave = tid >> 6, lane = tid & 63;
  const int quad = lane >> 4, l16 = lane & 15;
  const int m0 = blockIdx.x * 128, n0 = blockIdx.y * 128;
  const int wm = (wave >> 1) * 64, wn = (wave & 1) * 64;

  f32x4 acc[4][4];
#pragma unroll
  for (int i = 0; i < 4; ++i)
#pragma unroll
    for (int j = 0; j < 4; ++j) acc[i][j] = (f32x4){0.f, 0.f, 0.f, 0.f};

  const int srow = lane >> 2;
  const int scol = ((lane & 3) ^ ((lane >> 3) & 3)) * 8;
  const int c0 = wave * 2, c1 = c0 + 1;
  const int r0 = c0 * 16 + srow, r1 = c1 * 16 + srow;
  const bf16_t* Ag0 = A  + (size_t)(m0 + r0) * DM + scol;
  const bf16_t* Ag1 = A  + (size_t)(m0 + r1) * DM + scol;
  const bf16_t* Bg0 = Bw + (size_t)(n0 + r0) * DM + scol;
  const bf16_t* Bg1 = Bw + (size_t)(n0 + r1) * DM + scol;
  const int ld0 = c0 * 512, ld1 = c1 * 512;
  const int fcol = ((quad ^ ((l16 >> 1) & 3)) << 3);

  GEMM_LOOP

#pragma unroll
  for (int i = 0; i < 4; ++i)
#pragma unroll
    for (int j = 0; j < 4; ++j) {
      const int n  = n0 + wn + j * 16 + l16;
      const float bn = bias[n];
#pragma unroll
      for (int r = 0; r < 4; ++r) {
        const int m = m0 + wm + i * 16 + quad * 4 + r;
        out[(size_t)m * DM + n] = acc[i][j][r] + bn;
      }
    }
}

// ---------------------------------------------------------------------------
// Flash attention v9: KVBLK 64 -> 128 (16 tiles instead of 32). Rationale:
// per-tile fixed costs {1 vmcnt wait + 2 barriers + prefetch issue} amortize
// over 72 wave-MFMA instead of 36 (same lever as r9's QBLK doubling).
// Parameter-inheriting: same sync skeleton, 4 loads/thread/tile (K = 2
// rounds of 64 rows; V = 2 unchanged 64-k halves), steady vmcnt(4).
// sigma generalizes (bits>=5 pass through: sig(64+q)=64+sig(q)); mask is
// 4 u64s (k = 32f+8quad+4jj+r -> word f, byte 4jj+r). PV fused into the
// f-loop so only one pa-pair is live (VGPR ~111 <= 128 -> 2 blocks/CU x
// 8 waves = 16 waves/CU, LDS 64KB fits exactly 2). Accumulation order per
// O/Ol element stays k-ascending -> bit-identical to v8.
// ---------------------------------------------------------------------------
#define STAGE_KV(BUF, KK)                                                     \
  GLD16(kbase + (size_t)(KK) * HD + kgo0, &Kl[BUF][0] + ldk0);                \
  GLD16(kbase + (size_t)(KK) * HD + kgo1, &Kl[BUF][0] + ldk1);                \
  GLD16(vbase + (size_t)(vgo + (KK)), &Vl[BUF][0][0] + ldv);                  \
  GLD16(vbase + (size_t)(vgo + (KK) + 64), &Vl[BUF][1][0] + ldv);

#define ATTN_TILE128(K0)                                                      \
  {                                                                           \
    const bf16_t* Kc = &Kl[cur][0];                                           \
    _Pragma("unroll") for (int f = 0; f < 4; ++f) {                           \
      f32x4 S[2][2];                                                          \
      _Pragma("unroll") for (int jj = 0; jj < 2; ++jj) {                      \
        const int j = 2 * f + jj;                                             \
        const bf16x8 kb0 = *(const bf16x8*)(Kc + oA + j * 1024);              \
        const bf16x8 kb1 = *(const bf16x8*)(Kc + oB + j * 1024);              \
        _Pragma("unroll") for (int u = 0; u < 2; ++u) {                       \
          f32x4 a = (f32x4){0.f, 0.f, 0.f, 0.f};                              \
          a = mfma_16x16x32(kb0, qa[u][0], a);                                \
          a = mfma_16x16x32(kb1, qa[u][1], a);                                \
          _Pragma("unroll") for (int r = 0; r < 4; ++r)                       \
            S[u][jj][r] = __builtin_amdgcn_exp2f(a[r] * scale_l2e);           \
        }                                                                     \
      }                                                                       \
      if (has_mask) {                                                         \
        const uint64_t mm = *(const uint64_t*)(mrow + (K0) + f * 32 + quad * 8); \
        if (!__all(mm == 0)) {                                                \
          _Pragma("unroll") for (int jj = 0; jj < 2; ++jj)                    \
            _Pragma("unroll") for (int r = 0; r < 4; ++r)                     \
              if ((mm >> ((jj * 4 + r) * 8)) & 0xff) {                        \
                S[0][jj][r] = 0.f;                                            \
                S[1][jj][r] = 0.f;                                            \
              }                                                               \
        }                                                                     \
      }                                                                       \
      bf16x8 pa[2];                                                           \
      _Pragma("unroll") for (int u = 0; u < 2; ++u) {                         \
        _Pragma("unroll") for (int e = 0; e < 8; ++e)                         \
          pa[u][e] = (bf16_t)S[u][e >> 2][e & 3];                             \
        Ol[u] = mfma_16x16x32(pa[u], ones, Ol[u]);                            \
      }                                                                       \
      const bf16_t* Vc = &Vl[cur][f >> 1][0];                                 \
      const int vo = (f & 1) ? oB : oA;                                       \
      _Pragma("unroll") for (int jd = 0; jd < 4; ++jd) {                      \
        const bf16x8 vb = *(const bf16x8*)(Vc + vo + jd * 1024);              \
        _Pragma("unroll") for (int u = 0; u < 2; ++u)                         \
          O[u][jd] = mfma_16x16x32(pa[u], vb, O[u][jd]);                      \
      }                                                                       \
    }                                                                         \
  }

__global__ __launch_bounds__(512, 4) void attn_kernel(const bf16_t* __restrict__ qt,
                                                      const bf16_t* __restrict__ kt,
                                                      const bf16_t* __restrict__ vt,
                                                      const unsigned char* __restrict__ mask,
                                                      bf16_t* __restrict__ ctx) {
  __shared__ bf16_t Kl[2][128 * 64];       // [pos][d], col-blocks swizzled by pos&7
  __shared__ bf16_t Vl[2][2][64 * 64];     // [k-half][d][kk], swizzled by d&7
  __shared__ int mflag;
  // XCD remap over 512 blocks (8 q-tiles x 64 bh): XCD a <- bh in [8a,8a+8)
  const int L  = blockIdx.x + (blockIdx.y << 3);
  const int bh = ((L & 7) << 3) | ((L >> 3) & 7);
  const int q0 = (L >> 6) * 256;
  const int b = bh >> 4, h = bh & (NH - 1);
  const int tid = threadIdx.x;
  const int wave = tid >> 6, lane = tid & 63;   // wave 0..7
  const int quad = lane >> 4, l16 = lane & 15;
  const float scale_l2e = 0.125f * 1.44269504f;  // HD^-0.5 * log2(e)

  const bf16_t* kbase = kt + (size_t)bh * LSEQ * HD;
  const bf16_t* vbase = vt + (size_t)bh * HD * LSEQ;
  const unsigned char* mrow = mask + (size_t)b * LSEQ;

  if (tid == 0) mflag = 0;
  __syncthreads();
  // mask pre-scan: first 256 threads x 8B = entire 2048B row
  if (tid < 256) {
    const uint64_t mw = ((const uint64_t*)mrow)[tid];
    if (mw != 0) atomicOr(&mflag, 1);
  }

  // Q fragments (m=l16, k=quad*8+e), B-operand of swapped QK^T;
  // each wave owns 32 q-rows: q0 + wave*32 + u*16
  bf16x8 qa[2][2];
#pragma unroll
  for (int u = 0; u < 2; ++u) {
    const bf16_t* qrow = qt + (((size_t)bh * LSEQ) + q0 + wave * 32 + u * 16 + l16) * HD;
    qa[u][0] = *(const bf16x8*)(qrow + quad * 8);
    qa[u][1] = *(const bf16x8*)(qrow + 32 + quad * 8);
  }

  f32x4 O[2][4];
  f32x4 Ol[2];
#pragma unroll
  for (int u = 0; u < 2; ++u) {
    Ol[u] = (f32x4){0.f, 0.f, 0.f, 0.f};
#pragma unroll
    for (int j = 0; j < 4; ++j) O[u][j] = (f32x4){0.f, 0.f, 0.f, 0.f};
  }
  bf16x8 ones;
#pragma unroll
  for (int e = 0; e < 8; ++e) ones[e] = (bf16_t)1.0f;

  // --- hoisted per-lane offsets: 8 waves cover 64 rows per staging round ---
  const int srow8 = lane >> 3;  // 0..7 within 8-row chunk
  const int scb   = lane & 7;   // LDS col-block position
  const int p0 = wave * 8 + srow8;       // round-0 row (K pos / V d)
  const int g0 = (scb ^ srow8) * 8;      // p&7 == srow8 both rounds
  const int sig0 = ((p0 >> 5) << 5) | (((p0 >> 2) & 3) << 3) | (((p0 >> 4) & 1) << 2) | (p0 & 3);
  const int kgo0 = sig0 * HD + g0;       // K round 0 (rows 0..63)
  const int kgo1 = kgo0 + 64 * HD;       // K round 1 (rows 64..127): sig(64+q)=64+sig(q)
  const int vgo  = p0 * LSEQ + g0;       // V lane offset (both halves, +64 for h=1)
  const int ldk0 = wave * 512;           // K LDS dst, round 0
  const int ldk1 = wave * 512 + 4096;    // K LDS dst, round 1
  const int ldv  = wave * 512;           // V LDS dst (per half)

  // fragment-read offsets: sw = (j*16+l16)&7 == l16&7 for all j
  const int sw  = l16 & 7;
  const int oA  = l16 * 64 + ((quad ^ sw) << 3);
  const int oB  = l16 * 64 + (((quad + 4) ^ sw) << 3);

  // prologue: stage tiles 0 and 1 (4 loads/thread/tile; 8 in flight)
  STAGE_KV(0, 0)
  STAGE_KV(1, 128)

  // non-draining mflag sync: own atomic done (lgkm), then barrier, then read
  WAITL0; SBAR;
  const bool has_mask = (mflag != 0);

  int cur = 0;
  for (int t = 0; t < 14; ++t) {
    WAITV4; SBAR; SCHED0;
    ATTN_TILE128(t * 128);
    WAITL0; SBAR; SCHED0;
    STAGE_KV(cur, t * 128 + 256)
    cur ^= 1;
  }
  // t=14: own loads are oldest 4 of 8
  WAITV4; SBAR; SCHED0;
  ATTN_TILE128(14 * 128);
  cur ^= 1;
  // t=15: last tile
  WAITV0; SBAR; SCHED0;
  ATTN_TILE128(15 * 128);

  // epilogue: normalize and write ctx [B, LSEQ, NH*HD] bf16 (token-major)
#pragma unroll
  for (int u = 0; u < 2; ++u) {
    f32x4 linv;
#pragma unroll
    for (int r = 0; r < 4; ++r) linv[r] = 1.0f / Ol[u][r];
#pragma unroll
    for (int jd = 0; jd < 4; ++jd)
#pragma unroll
      for (int r = 0; r < 4; ++r) {
        const int l = q0 + wave * 32 + u * 16 + quad * 4 + r;
        const int d = h * HD + jd * 16 + l16;
        const float o = O[u][jd][r] * linv[r];
        ctx[((size_t)b * LSEQ + l) * DM + d] = (bf16_t)o;
      }
  }
}

// ---------------------------------------------------------------------------
extern "C" void kernel_launch(void* const* d_in, const int* in_sizes, int n_in,
                              void* d_out, int out_size, void* d_ws, size_t ws_size,
                              hipStream_t stream) {
  (void)in_sizes; (void)n_in; (void)out_size; (void)ws_size;
  const float* query = (const float*)d_in[0];
  const float* key   = (const float*)d_in[1];
  const float* value = (const float*)d_in[2];
  const float* cos_q = (const float*)d_in[3];
  const float* sin_q = (const float*)d_in[4];
  const float* cos_k = (const float*)d_in[5];
  const float* sin_k = (const float*)d_in[6];
  const unsigned char* mask = (const unsigned char*)d_in[7];
  const float* Wq = (const float*)d_in[8];
  const float* bq = (const float*)d_in[9];
  const float* Wk = (const float*)d_in[10];
  const float* bk = (const float*)d_in[11];
  const float* Wv = (const float*)d_in[12];
  const float* bv = (const float*)d_in[13];
  const float* Wo = (const float*)d_in[14];
  const float* bo = (const float*)d_in[15];
  float* out = (float*)d_out;

  const size_t ACT = (size_t)TOKENS * DM;  // 8388608
  const size_t WEL = (size_t)DM * DM;      // 1048576
  const size_t CSN = (size_t)TOKENS * HD;  // 524288 float2 per table

  bf16_t* p   = (bf16_t*)d_ws;
  bf16_t* xq  = p; p += ACT;    // xq,xk,xv contiguous (prep dst / qkv A base)
  bf16_t* xk  = p; p += ACT;
  bf16_t* xv  = p; p += ACT;
  bf16_t* wqb = p; p += WEL;    // wqb..wob contiguous (prep dst / qkv W base)
  bf16_t* wkb = p; p += WEL;
  bf16_t* wvb = p; p += WEL;
  bf16_t* wob = p; p += WEL;
  bf16_t* qtb = p; p += ACT;
  bf16_t* ktb = p; p += ACT;
  bf16_t* vtb = p; p += ACT;
  bf16_t* ctx = xk;  // alias: xk dead after qkv proj
  (void)xv; (void)wkb; (void)wvb;

  // cos/sin float2 tables live in d_out (32MB f32): only out_gemm writes
  // d_out, at the very end — free scratch until then.
  float2* csq = (float2*)out;        // 4MB
  float2* csk = csq + CSN;           // 4MB

  // fused prep: casts + cs-table build, ONE dispatch
  prep_kernel<<<dim3(29696), 256, 0, stream>>>(query, key, value, Wq, Wk, Wv, Wo,
                                               cos_q, sin_q, cos_k, sin_k,
                                               xq, wqb, csq);

  // fused q/k/v projections (one dispatch, z = which projection)
  qkv_proj_kernel<<<dim3(TOKENS / 128, DM / 128, 3), 256, 0, stream>>>(
      xq, wqb, bq, bk, bv, csq, csk, qtb, ktb, vtb);

  // flash attention -> ctx [B, LSEQ, DM] bf16 (QBLK=256, KVBLK=128, 8 waves)
  attn_kernel<<<dim3(LSEQ / 256, B_DIM * NH), 512, 0, stream>>>(qtb, ktb, vtb, mask, ctx);

  // output projection -> f32 d_out (overwrites the cs scratch)
  out_gemm_kernel<<<dim3(TOKENS / 128, DM / 128), 256, 0, stream>>>(ctx, wob, bo, out);
}